// Round 5
// baseline (1140.116 us; speedup 1.0000x reference)
//
#include <hip/hip_runtime.h>
#include <hip/hip_bf16.h>
#include <math.h>
#include <stdint.h>

// Problem constants
#define DIM 4096
#define N_HEADS 32
#define N_KV_HEADS 8
#define HEAD_DIM 128
#define BSZ 2
#define SEQLEN 2048
#define BS (BSZ * SEQLEN)               // 4096 rows
#define KV_DIM (N_KV_HEADS * HEAD_DIM)  // 1024

typedef unsigned short u16;
typedef __attribute__((ext_vector_type(8))) short bf16x8;
typedef __attribute__((ext_vector_type(4))) float f32x4;
typedef __attribute__((ext_vector_type(16))) float f32x16;
typedef __attribute__((ext_vector_type(8))) unsigned short u16x8;
typedef __attribute__((ext_vector_type(4))) unsigned short u16x4;

__device__ __forceinline__ u16 f2bf(float f) {
    __hip_bfloat16 h = __float2bfloat16(f);
    return *reinterpret_cast<u16*>(&h);
}
__device__ __forceinline__ float bf2f(u16 u) {
    __hip_bfloat16 h;
    *reinterpret_cast<u16*>(&h) = u;
    return __bfloat162float(h);
}
__device__ __forceinline__ uint32_t packbf(float a, float b) {
    return (uint32_t)f2bf(a) | ((uint32_t)f2bf(b) << 16);
}

#define GLOAD_LDS16(gptr, lptr)                                                      \
    __builtin_amdgcn_global_load_lds(                                                \
        reinterpret_cast<const __attribute__((address_space(1))) uint32_t*>(         \
            reinterpret_cast<uintptr_t>(gptr)),                                      \
        reinterpret_cast<__attribute__((address_space(3))) uint32_t*>(               \
            reinterpret_cast<uintptr_t>(lptr)),                                      \
        16, 0, 0)

// ---------------------------------------------------------------------------
// cvt: fp32 -> bf16, 4 elems/thread
// ---------------------------------------------------------------------------
__global__ void cvt_f32_bf16(const float* __restrict__ in, u16* __restrict__ out, int n4) {
    int i = blockIdx.x * blockDim.x + threadIdx.x;
    if (i >= n4) return;
    float4 v = reinterpret_cast<const float4*>(in)[i];
    u16x4 o;
    o.x = f2bf(v.x); o.y = f2bf(v.y); o.z = f2bf(v.z); o.w = f2bf(v.w);
    reinterpret_cast<u16x4*>(out)[i] = o;
}

// ---------------------------------------------------------------------------
// transpose + cvt: in[K][N] fp32 -> out[N][K] bf16.  block (32,8), 32x32 tile.
// ---------------------------------------------------------------------------
__global__ __launch_bounds__(256) void transpose_f32_bf16(const float* __restrict__ in,
                                                          u16* __restrict__ out,
                                                          int K, int N) {
    __shared__ float tile[32][33];
    const int tx = threadIdx.x, ty = threadIdx.y;
    const int n0 = blockIdx.x * 32, k0 = blockIdx.y * 32;
#pragma unroll
    for (int i = 0; i < 4; ++i)
        tile[ty + 8 * i][tx] = in[(size_t)(k0 + ty + 8 * i) * N + n0 + tx];
    __syncthreads();
#pragma unroll
    for (int i = 0; i < 4; ++i)
        out[(size_t)(n0 + ty + 8 * i) * K + k0 + tx] = f2bf(tile[tx][ty + 8 * i]);
}

// ---------------------------------------------------------------------------
// transpose bf16 V into per-(b,hkv) head-major layout:
//   xv  [BS][KV_DIM]  (row = b*S + k, col = hkv*128 + d)
//   xvT [(b*8+hkv)*128 + d][SEQLEN]  (col = k)
// ---------------------------------------------------------------------------
__global__ __launch_bounds__(256) void transpose_v_bf16(const u16* __restrict__ xv,
                                                        u16* __restrict__ xvT) {
    __shared__ u16 tile[32][33];
    const int tx = threadIdx.x, ty = threadIdx.y;
    const int k0 = blockIdx.x * 32, d0 = blockIdx.y * 32;
    const int bh = blockIdx.z;
    const int b = bh >> 3, hkv = bh & 7;
#pragma unroll
    for (int i = 0; i < 4; ++i)
        tile[ty + 8 * i][tx] =
            xv[((size_t)(b * SEQLEN) + k0 + ty + 8 * i) * KV_DIM + hkv * HEAD_DIM + d0 + tx];
    __syncthreads();
#pragma unroll
    for (int i = 0; i < 4; ++i)
        xvT[((size_t)bh * HEAD_DIM + d0 + ty + 8 * i) * SEQLEN + k0 + tx] = tile[tx][ty + 8 * i];
}

// ---------------------------------------------------------------------------
// MFMA bf16 GEMM:  C[M,N] = A[M,K] @ B[K,N]  with B given TRANSPOSED (BT[N,K]).
// (unchanged — verified good)
// ---------------------------------------------------------------------------
template <bool OUT_BF16>
__global__ __launch_bounds__(256) void gemm_mfma_bt(const u16* __restrict__ A,
                                                    const u16* __restrict__ BT,
                                                    void* __restrict__ Cv,
                                                    int M, int N, int K) {
    __shared__ __align__(16) u16 Al[128 * 64];
    __shared__ __align__(16) u16 Bl[128 * 64];

    const int tid  = threadIdx.x;
    const int wave = tid >> 6;
    const int lane = tid & 63;
    const int quad = lane >> 4;
    const int lm   = lane & 15;
    const size_t bm = (size_t)blockIdx.y * 128;
    const size_t bn = (size_t)blockIdx.x * 128;
    const int wm = (wave & 1) * 64;
    const int wn = (wave >> 1) * 64;

    const int slot = lane & 7;
    const int lrow = lane >> 3;
    const int csw  = slot ^ (lrow & 7);

    f32x4 acc[4][4] = {};

    for (int k0 = 0; k0 < K; k0 += 64) {
        __syncthreads();
#pragma unroll
        for (int i = 0; i < 4; ++i) {
            const int mloc = wave * 32 + i * 8 + lrow;
            const u16* gA = A  + (bm + mloc) * (size_t)K + k0 + csw * 8;
            const u16* gB = BT + (bn + mloc) * (size_t)K + k0 + csw * 8;
            u16* lA = &Al[(mloc * 8 + slot) * 8];
            u16* lB = &Bl[(mloc * 8 + slot) * 8];
            GLOAD_LDS16(gA, lA);
            GLOAD_LDS16(gB, lB);
        }
        __syncthreads();

#pragma unroll
        for (int ks8 = 0; ks8 < 8; ks8 += 4) {
            bf16x8 af[4], bfr[4];
            const int cc = ks8 + quad;
#pragma unroll
            for (int i = 0; i < 4; ++i) {
                const int m = wm + 16 * i + lm;
                af[i]  = *(const bf16x8*)&Al[(m * 8 + (cc ^ (m & 7))) * 8];
                const int n = wn + 16 * i + lm;
                bfr[i] = *(const bf16x8*)&Bl[(n * 8 + (cc ^ (n & 7))) * 8];
            }
#pragma unroll
            for (int i = 0; i < 4; ++i)
#pragma unroll
                for (int j = 0; j < 4; ++j)
                    acc[i][j] = __builtin_amdgcn_mfma_f32_16x16x32_bf16(af[i], bfr[j], acc[i][j], 0, 0, 0);
        }
    }

#pragma unroll
    for (int i = 0; i < 4; ++i) {
        const int mrow = wm + 16 * i + quad * 4;
#pragma unroll
        for (int j = 0; j < 4; ++j) {
            const int ncol = wn + 16 * j + lm;
#pragma unroll
            for (int r = 0; r < 4; ++r) {
                const size_t off = (bm + mrow + r) * (size_t)N + bn + ncol;
                const float v = acc[i][j][r];
                if constexpr (OUT_BF16) ((u16*)Cv)[off] = f2bf(v);
                else                    ((float*)Cv)[off] = v;
            }
        }
    }
}

// ---------------------------------------------------------------------------
// RoPE (interleaved pairs), in-place on bf16. t layout: (BS, n_heads*128).
// ---------------------------------------------------------------------------
__global__ void rope_kernel(u16* __restrict__ t,
                            const float* __restrict__ cosb,
                            const float* __restrict__ sinb,
                            int n_heads, int total_pairs) {
    int idx = blockIdx.x * blockDim.x + threadIdx.x;
    if (idx >= total_pairs) return;
    int p = idx & 63;
    int h = (idx >> 6) % n_heads;
    int bs = idx / (64 * n_heads);
    int s = bs & (SEQLEN - 1);        // start_pos = 0

    float c = cosb[s * 64 + p];
    float sn = sinb[s * 64 + p];

    size_t base = (size_t)bs * (n_heads * HEAD_DIM) + h * HEAD_DIM + 2 * p;
    float e = bf2f(t[base]);
    float o = bf2f(t[base + 1]);
    t[base]     = f2bf(e * c - o * sn);
    t[base + 1] = f2bf(e * sn + o * c);
}

// ---------------------------------------------------------------------------
// MFMA flash attention — 32x32x16, swapped QK^T, in-register softmax,
// GQA head-pair sharing.
//   grid (S/128, N_HEADS/2, BSZ) heavy-first, 512 threads = 8 waves.
//   Waves 0-3 = head 2hp, waves 4-7 = head 2hp+1 (SAME kv head): one K/V
//   stage serves both heads -> staging bytes + barriers per MFMA halved.
//   Wave w owns q rows [128*qt + 32*(w&3), +32); lane's q = base + (lane&31).
//   KVBLK=64; K LDS [64][128], V^T LDS [128][64], chunk-XOR swizzled src.
//   Swapped QK^T -> q lane-local softmax (in-reg + 1 shfl_xor(32)).
//   Defer-max (T13): skip alpha-rescale when tile max growth (scaled) <= 8.
//   In-register P->A-frag repack (partner word exchange); PV as O^T.
// Fragment layouts (32x32x16): A row=lane&31, k=(lane>>5)*8+j; B k=(lane>>5)*8+j,
//   col=lane&31; C col=lane&31, row=(reg&3)+8*(reg>>2)+4*(lane>>5). [m74/m101]
// ---------------------------------------------------------------------------
#define OPAD 132   // O-stage row stride (u16): 264B -> 2-way (free) bank pattern

__global__ __launch_bounds__(512, 4) void flash_attn_mfma(const u16* __restrict__ xq,
                                                          const u16* __restrict__ xk,
                                                          const u16* __restrict__ xvT,
                                                          u16* __restrict__ ctx) {
    __shared__ __align__(16) u16 LB[128 * OPAD];   // 33792 B; Ks/Vt overlay + O-stage
    u16* Ks = LB;                  // [64 k][16 chunks][8]  = 8192 u16
    u16* Vt = LB + 64 * 16 * 8;    // [128 d][8 chunks][8]  = 8192 u16

    const int qt  = (int)gridDim.x - 1 - (int)blockIdx.x;  // heavy-first
    const int hp  = blockIdx.y;         // head pair: heads 2hp, 2hp+1
    const int b   = blockIdx.z;
    const int hkv = hp >> 1;            // shared kv head of the pair

    const int tid  = threadIdx.x;
    const int wave = tid >> 6;
    const int lane = tid & 63;
    const int hh   = lane >> 5;         // half (0/1)
    const int l31  = lane & 31;
    const int h    = 2 * hp + (wave >> 2);   // this wave's q head
    const int q0   = qt * 128;
    const int wq0  = q0 + (wave & 3) * 32;
    const int qrow = wq0 + l31;         // this lane's q row (in seq)
    const float C = 0.08838834764831845f * 1.44269504088896f;  // (1/sqrt(128))*log2(e)

    // Q fragments (B-operand): qf[step] = Q[qrow][16*step + 8*hh .. +8]
    bf16x8 qf[8];
    {
        const u16* qp = xq + ((size_t)(b * SEQLEN) + qrow) * DIM + h * HEAD_DIM + hh * 8;
#pragma unroll
        for (int s = 0; s < 8; ++s) qf[s] = *(const bf16x8*)(qp + 16 * s);
    }

    const u16* xkb = xk + (size_t)(b * SEQLEN) * KV_DIM + hkv * HEAD_DIM;
    const u16* xvb = xvT + ((size_t)(b * N_KV_HEADS + hkv)) * HEAD_DIM * SEQLEN;

    float m_i = -INFINITY, l_i = 0.f;
    f32x16 acc[4] = {};   // acc[dt]: O^T, d = 32*dt + (reg&3)+8*(reg>>2)+4*hh, col q = qrow

    const int nkt = 2 * qt + 2;
    for (int kt = 0; kt < nkt; ++kt) {
        const int k0 = kt * 64;
        __syncthreads();
        // --- stage K [64][128] and V^T [128][64]; src chunk-XOR pre-swizzled.
        //     512 threads: 2 K-chunks + 2 V-chunks each ---
#pragma unroll
        for (int i = 0; i < 2; ++i) {
            const int ci = i * 512 + tid;            // 0..1023
            const int kr = ci >> 4, cp = ci & 15;
            GLOAD_LDS16(xkb + (size_t)(k0 + kr) * KV_DIM + (cp ^ (kr & 7)) * 8, &Ks[ci * 8]);
            const int dr = ci >> 3, cq = ci & 7;
            GLOAD_LDS16(xvb + (size_t)dr * SEQLEN + k0 + (cq ^ (dr & 7)) * 8, &Vt[ci * 8]);
        }
        __syncthreads();

        if (k0 > wq0 + 31) continue;   // fully masked for this wave (stage already done)

        // --- QK^T (swapped): s[ct] = S^T[k=32ct.., q] ---
        f32x16 s[2] = {};
        __builtin_amdgcn_s_setprio(1);
#pragma unroll
        for (int step = 0; step < 8; ++step) {
#pragma unroll
            for (int ct = 0; ct < 2; ++ct) {
                const int krow = ct * 32 + l31;
                const int c = 2 * step + hh;
                bf16x8 kf = *(const bf16x8*)&Ks[(krow * 16 + (c ^ (krow & 7))) * 8];
                s[ct] = __builtin_amdgcn_mfma_f32_32x32x16_bf16(kf, qf[step], s[ct], 0, 0, 0);
            }
        }
        __builtin_amdgcn_s_setprio(0);

        // --- causal mask (raw-score domain); only near-diagonal tiles ---
        if (k0 + 63 > wq0) {
#pragma unroll
            for (int ct = 0; ct < 2; ++ct)
#pragma unroll
                for (int r = 0; r < 16; ++r) {
                    const int kg = k0 + ct * 32 + (r & 3) + 8 * (r >> 2) + 4 * hh;
                    if (kg > qrow) s[ct][r] = -1e30f;
                }
        }

        // --- online softmax: lane-local reduce + one partner exchange ---
        float mx = s[0][0];
#pragma unroll
        for (int r = 1; r < 16; ++r) mx = fmaxf(mx, s[0][r]);
#pragma unroll
        for (int r = 0; r < 16; ++r) mx = fmaxf(mx, s[1][r]);
        mx = fmaxf(mx, __shfl_xor(mx, 32));

        // defer-max (T13): if every lane's growth (scaled) <= 8, keep old max
        const bool keep = __all((mx - m_i) * C <= 8.0f);
        float alpha = 1.0f;
        if (!keep) {
            const float nm = fmaxf(m_i, mx);
            alpha = exp2f((m_i - nm) * C);
            m_i = nm;
        }
        float sum = 0.f;
#pragma unroll
        for (int ct = 0; ct < 2; ++ct)
#pragma unroll
            for (int r = 0; r < 16; ++r) {
                const float p = exp2f((s[ct][r] - m_i) * C);
                s[ct][r] = p;
                sum += p;
            }
        sum += __shfl_xor(sum, 32);
        l_i = alpha * l_i + sum;

        // --- P -> PV B-operand frags, in-register (partner word exchange) ---
        bf16x8 pa[4];
#pragma unroll
        for (int ct = 0; ct < 2; ++ct)
#pragma unroll
            for (int kss = 0; kss < 2; ++kss) {
                const int base = 8 * kss;
                const uint32_t lo0 = packbf(s[ct][base + 0], s[ct][base + 1]);
                const uint32_t lo1 = packbf(s[ct][base + 2], s[ct][base + 3]);
                const uint32_t hi0 = packbf(s[ct][base + 4], s[ct][base + 5]);
                const uint32_t hi1 = packbf(s[ct][base + 6], s[ct][base + 7]);
                const uint32_t s0 = hh ? lo0 : hi0;
                const uint32_t s1 = hh ? lo1 : hi1;
                const uint32_t r0 = (uint32_t)__shfl_xor((int)s0, 32);
                const uint32_t r1 = (uint32_t)__shfl_xor((int)s1, 32);
                union { uint32_t u[4]; bf16x8 v; } pu;
                pu.u[0] = hh ? r0 : lo0;
                pu.u[1] = hh ? r1 : lo1;
                pu.u[2] = hh ? hi0 : r0;
                pu.u[3] = hh ? hi1 : r1;
                pa[2 * ct + kss] = pu.v;
            }

        // --- rescale O (skipped when defer-max kept old m), then PV ---
        if (!keep) {
#pragma unroll
            for (int dt = 0; dt < 4; ++dt)
#pragma unroll
                for (int r = 0; r < 16; ++r) acc[dt][r] *= alpha;
        }

        __builtin_amdgcn_s_setprio(1);
#pragma unroll
        for (int ks = 0; ks < 4; ++ks)
#pragma unroll
            for (int dt = 0; dt < 4; ++dt) {
                const int vrow = dt * 32 + l31;
                const int c = 2 * ks + hh;
                bf16x8 vf = *(const bf16x8*)&Vt[(vrow * 8 + (c ^ (vrow & 7))) * 8];
                acc[dt] = __builtin_amdgcn_mfma_f32_32x32x16_bf16(vf, pa[ks], acc[dt], 0, 0, 0);
            }
        __builtin_amdgcn_s_setprio(0);
    }

    // --- epilogue: two rounds (one per head of the pair) through LB ---
    __syncthreads();                        // K/V reads complete block-wide
    const float inv_l = 1.0f / l_i;
#pragma unroll
    for (int g = 0; g < 2; ++g) {
        if ((wave >> 2) == g) {
            const int q_l = (wave & 3) * 32 + l31;
#pragma unroll
            for (int dt = 0; dt < 4; ++dt)
#pragma unroll
                for (int rp = 0; rp < 8; ++rp) {
                    const int reg = 2 * rp;
                    const int d = dt * 32 + (reg & 3) + 8 * (reg >> 2) + 4 * hh;
                    *(uint32_t*)&LB[q_l * OPAD + d] =
                        packbf(acc[dt][reg] * inv_l, acc[dt][reg + 1] * inv_l);
                }
        }
        __syncthreads();
        {
            const int qr = tid >> 2, seg = tid & 3;   // 128 rows x 4 segs of 32
            u16* op = ctx + ((size_t)(b * SEQLEN) + q0 + qr) * DIM
                      + (2 * hp + g) * HEAD_DIM + seg * 32;
            const u16* lp = &LB[qr * OPAD + seg * 32];
#pragma unroll
            for (int c2 = 0; c2 < 8; ++c2)
                *(u16x4*)(op + 4 * c2) = *(const u16x4*)(lp + 4 * c2);
        }
        __syncthreads();
    }
}

// ---------------------------------------------------------------------------
// kernel_launch
// ---------------------------------------------------------------------------
extern "C" void kernel_launch(void* const* d_in, const int* in_sizes, int n_in,
                              void* d_out, int out_size, void* d_ws, size_t ws_size,
                              hipStream_t stream) {
    const float* x   = (const float*)d_in[0];
    const float* wq  = (const float*)d_in[1];
    const float* wk  = (const float*)d_in[2];
    const float* wv  = (const float*)d_in[3];
    const float* wo  = (const float*)d_in[4];
    const float* fc  = (const float*)d_in[5];
    const float* fs  = (const float*)d_in[6];
    float* out = (float*)d_out;

    // ws carve-up: exactly 160 MiB total
    u16* x_bf = (u16*)d_ws;                       // [4096][4096]
    u16* wqT  = x_bf + (size_t)BS * DIM;          // [4096][4096]
    u16* wkT  = wqT + (size_t)DIM * DIM;          // [1024][4096]
    u16* wvT  = wkT + (size_t)KV_DIM * DIM;       // [1024][4096]
    u16* woT  = wvT + (size_t)KV_DIM * DIM;       // [4096][4096]
    u16* xq   = woT + (size_t)DIM * DIM;          // [4096][4096]
    u16* xk   = xq + (size_t)BS * DIM;            // [4096][1024]
    u16* xv   = xk + (size_t)BS * KV_DIM;         // [4096][1024]
    u16* ctx  = x_bf;                             // alias x_bf (dead after QKV GEMMs)
    u16* xvT  = wvT;                              // alias wvT (dead after V projection)

    // 0) converts
    {
        int n4 = BS * DIM / 4;
        cvt_f32_bf16<<<(n4 + 255) / 256, 256, 0, stream>>>(x, x_bf, n4);
        dim3 blk(32, 8);
        transpose_f32_bf16<<<dim3(DIM / 32, DIM / 32), blk, 0, stream>>>(wq, wqT, DIM, DIM);
        transpose_f32_bf16<<<dim3(KV_DIM / 32, DIM / 32), blk, 0, stream>>>(wk, wkT, DIM, KV_DIM);
        transpose_f32_bf16<<<dim3(KV_DIM / 32, DIM / 32), blk, 0, stream>>>(wv, wvT, DIM, KV_DIM);
        transpose_f32_bf16<<<dim3(DIM / 32, DIM / 32), blk, 0, stream>>>(wo, woT, DIM, DIM);
    }

    // 1) QKV projections (MFMA)
    gemm_mfma_bt<true><<<dim3(DIM / 128, BS / 128), 256, 0, stream>>>(x_bf, wqT, xq, BS, DIM, DIM);
    gemm_mfma_bt<true><<<dim3(KV_DIM / 128, BS / 128), 256, 0, stream>>>(x_bf, wkT, xk, BS, KV_DIM, DIM);
    gemm_mfma_bt<true><<<dim3(KV_DIM / 128, BS / 128), 256, 0, stream>>>(x_bf, wvT, xv, BS, KV_DIM, DIM);

    // 1b) V -> head-major transposed layout (overwrites dead wvT)
    transpose_v_bf16<<<dim3(SEQLEN / 32, HEAD_DIM / 32, BSZ * N_KV_HEADS), dim3(32, 8), 0, stream>>>(xv, xvT);

    // 2) RoPE (Q and K only)
    {
        int total_q = BS * N_HEADS * 64;
        rope_kernel<<<(total_q + 255) / 256, 256, 0, stream>>>(xq, fc, fs, N_HEADS, total_q);
        int total_k = BS * N_KV_HEADS * 64;
        rope_kernel<<<(total_k + 255) / 256, 256, 0, stream>>>(xk, fc, fs, N_KV_HEADS, total_k);
    }

    // 3) MFMA flash attention (32x32, swapped QK^T, GQA head-pair) -> bf16 ctx
    flash_attn_mfma<<<dim3(SEQLEN / 128, N_HEADS / 2, BSZ), 512, 0, stream>>>(xq, xk, xvT, ctx);

    // 4) Output projection (MFMA) -> fp32 out
    gemm_mfma_bt<false><<<dim3(DIM / 128, BS / 128), 256, 0, stream>>>(ctx, woT, out, BS, DIM, DIM);
}